// Round 1
// baseline (4639.979 us; speedup 1.0000x reference)
//
#include <hip/hip_runtime.h>
#include <hip/hip_bf16.h>
#include <stdint.h>

// Problem constants
#define T_STEPS 128
#define BATCH   2048
#define IN_DIM  18
#define HID     256
#define G3      768   // 3*HID

// Tiling
#define NT   48              // 768 / 16 n-tiles
#define KT0  9               // layer0 k-tiles: 1 (x padded to 32) + 8 (h1, K=256)
#define KT1  16              // layer1 k-tiles: 8 (W_ih1) + 8 (W_hh1)
#define L0_FRAGS (NT * KT0)  // 432
#define L1_FRAGS (NT * KT1)  // 768
#define TOT_FRAGS (L0_FRAGS + L1_FRAGS)  // 1200 fragments x 1KB = 1.2 MB in d_ws

#define NBLK 128
#define TPB  512             // 8 waves
#define ROWS 16              // batch rows per block (full 16x16 MFMA M-tile)
#define PITCH0 288           // bf16 pitch: 144 dwords % 32 == 16 -> good bank spread
#define PITCH1 544           // 512 + 32 pad: 272 dwords % 32 == 16
#define HP     260           // fp32 h-state pitch (breaks power-of-2 stride)

using frag_ab = __attribute__((ext_vector_type(8))) short;  // 8 x bf16 (4 VGPRs)
using f32x4   = __attribute__((ext_vector_type(4))) float;

__device__ __forceinline__ unsigned short f2bf(float f) {
  unsigned int u = __float_as_uint(f);
  u = (u + 0x7fffu + ((u >> 16) & 1u)) >> 16;  // RNE
  return (unsigned short)u;
}

__device__ __forceinline__ float sigmoidf_(float v) {
  return 1.f / (1.f + __expf(-v));
}
__device__ __forceinline__ float tanhf_(float v) {
  float a = fabsf(v);
  float e = __expf(-2.f * a);
  float r = (1.f - e) / (1.f + e);
  return v < 0.f ? -r : r;
}

__device__ __forceinline__ f32x4 mfma16(frag_ab a, frag_ab b, f32x4 c) {
  return __builtin_amdgcn_mfma_f32_16x16x32_bf16(a, b, c, 0, 0, 0);
}

// ---------------------------------------------------------------------------
// Prologue: fp32 weights -> bf16, permuted into exact MFMA B-fragment order.
// Fragment f (1KB): lane L, elems j=0..7 hold B[k = kt*32 + (L>>4)*8 + j]
//                                          [n = ntile*16 + (L&15)]
// where B[k][n] = W[n][k]  (hg = h @ W^T).
// Layer0 frag(n,kt): kt==0 -> [W_ih0 | zero-pad to K=32]; kt=1..8 -> W_hh0.
// Layer1 frag(n,kt): kt<8 -> W_ih1; kt>=8 -> W_hh1.
// ---------------------------------------------------------------------------
__global__ __launch_bounds__(256) void repack_w(
    const float* __restrict__ Wih0, const float* __restrict__ Whh0,
    const float* __restrict__ Wih1, const float* __restrict__ Whh1,
    unsigned short* __restrict__ wq)
{
  int g = blockIdx.x * 256 + threadIdx.x;
  if (g >= TOT_FRAGS * 64) return;
  int f = g >> 6;
  int L = g & 63;
  int q = L >> 4, c16 = L & 15;
  unsigned short v[8];
  if (f < L0_FRAGS) {
    int n = f / KT0, kt = f - n * KT0;
    int col = n * 16 + c16;
    if (kt == 0) {
      #pragma unroll
      for (int j = 0; j < 8; ++j) {
        int k = q * 8 + j;
        v[j] = (k < IN_DIM) ? f2bf(Wih0[col * IN_DIM + k]) : (unsigned short)0;
      }
    } else {
      int kb = (kt - 1) * 32 + q * 8;
      #pragma unroll
      for (int j = 0; j < 8; ++j) v[j] = f2bf(Whh0[col * HID + kb + j]);
    }
  } else {
    int f1 = f - L0_FRAGS;
    int n = f1 / KT1, kt = f1 - n * KT1;
    int col = n * 16 + c16;
    const float* __restrict__ W = (kt < 8) ? Wih1 : Whh1;
    int kb = (kt & 7) * 32 + q * 8;
    #pragma unroll
    for (int j = 0; j < 8; ++j) v[j] = f2bf(W[col * HID + kb + j]);
  }
  frag_ab pv;
  #pragma unroll
  for (int j = 0; j < 8; ++j) pv[j] = (short)v[j];
  *(frag_ab*)((char*)wq + ((size_t)f << 10) + (size_t)(L << 4)) = pv;
}

// ---------------------------------------------------------------------------
// Persistent fused 2-layer GRU + FC head. One block owns ROWS batch rows,
// runs all 128 timesteps locally. h-state fp32 master in LDS; bf16 copies
// feed MFMA. Weights stream from L2 in fragment order (coalesced dwordx4).
// ---------------------------------------------------------------------------
__global__ __launch_bounds__(TPB, 2) void gru_fused(
    const float* __restrict__ x,
    const float* __restrict__ bih0, const float* __restrict__ bhh0,
    const float* __restrict__ bih1, const float* __restrict__ bhh1,
    const float* __restrict__ fcw,  const float* __restrict__ fcb,
    const unsigned short* __restrict__ wq,
    float* __restrict__ out)
{
  __shared__ __align__(16) unsigned short A0[ROWS][PITCH0]; // [x pad32 | h1] bf16
  __shared__ __align__(16) unsigned short A1[ROWS][PITCH1]; // [h1_new | h2 | pad] bf16
  __shared__ float h1f[ROWS][HP];
  __shared__ float h2f[ROWS][HP];
  __shared__ float sb[4 * G3 + 4 * HID + 4]; // bih0,bhh0,bih1,bhh1,fcw,fcb

  const int tid  = threadIdx.x;
  const int wave = tid >> 6;
  const int lane = tid & 63;
  const int q    = lane >> 4;
  const int c16  = lane & 15;
  const int brow0 = blockIdx.x * ROWS;

  for (int i = tid; i < ROWS * PITCH0; i += TPB) (&A0[0][0])[i] = 0;
  for (int i = tid; i < ROWS * PITCH1; i += TPB) (&A1[0][0])[i] = 0;
  for (int i = tid; i < ROWS * HP; i += TPB) { (&h1f[0][0])[i] = 0.f; (&h2f[0][0])[i] = 0.f; }
  for (int i = tid; i < G3; i += TPB) {
    sb[i]          = bih0[i];
    sb[G3 + i]     = bhh0[i];
    sb[2*G3 + i]   = bih1[i];
    sb[3*G3 + i]   = bhh1[i];
  }
  for (int i = tid; i < 4 * HID; i += TPB) sb[4*G3 + i] = fcw[i];
  if (tid < 4) sb[4*G3 + 4*HID + tid] = fcb[tid];
  __syncthreads();

  const char* wb = (const char*)wq;
  const int j0 = wave * 2;  // each wave owns 2 gate-triples (2 x 16 h-cols)

  for (int t = 0; t < T_STEPS; ++t) {
    // ---- stage x_t into A0[:, 0:18] (288 contiguous floats, coalesced) ----
    if (tid < ROWS * IN_DIM) {
      float v = x[(size_t)(t * BATCH + brow0) * IN_DIM + tid];
      int r = tid / IN_DIM;
      int c = tid - r * IN_DIM;
      A0[r][c] = f2bf(v);
    }
    __syncthreads();  // s1: x + prev h1 visible

    // ---- layer 0: A-fragments (shared across this wave's n-tiles) ----
    frag_ab a0[KT0];
    #pragma unroll
    for (int kt = 0; kt < KT0; ++kt)
      a0[kt] = *(const frag_ab*)&A0[c16][kt * 32 + q * 8];
    __syncthreads();  // s2: all A0 reads done before epilogue stores

    #pragma unroll
    for (int jj = 0; jj < 2; ++jj) {
      const int j = j0 + jj;
      const char* pr = wb + ((size_t)((j     ) * KT0) << 10) + (size_t)(lane << 4);
      const char* pz = wb + ((size_t)((16 + j) * KT0) << 10) + (size_t)(lane << 4);
      const char* pn = wb + ((size_t)((32 + j) * KT0) << 10) + (size_t)(lane << 4);
      f32x4 ar = {0,0,0,0}, az = {0,0,0,0}, anx = {0,0,0,0}, anh = {0,0,0,0};
      #pragma unroll
      for (int kt = 0; kt < KT0; ++kt) {
        frag_ab br = *(const frag_ab*)(pr + kt * 1024);
        frag_ab bz = *(const frag_ab*)(pz + kt * 1024);
        frag_ab bn = *(const frag_ab*)(pn + kt * 1024);
        ar = mfma16(a0[kt], br, ar);
        az = mfma16(a0[kt], bz, az);
        if (kt == 0) anx = mfma16(a0[kt], bn, anx);  // x-part of n-gate
        else         anh = mfma16(a0[kt], bn, anh);  // h-part of n-gate
      }
      const int c   = j * 16 + c16;  // h-column 0..255
      const float bri = sb[c],           brh = sb[G3 + c];
      const float bzi = sb[HID + c],     bzh = sb[G3 + HID + c];
      const float bni = sb[2*HID + c],   bnh = sb[G3 + 2*HID + c];
      #pragma unroll
      for (int rr = 0; rr < 4; ++rr) {
        int row = q * 4 + rr;  // C/D: row=(lane>>4)*4+reg, col=lane&15
        float rg = sigmoidf_(ar[rr] + bri + brh);
        float zg = sigmoidf_(az[rr] + bzi + bzh);
        float ng = tanhf_(anx[rr] + bni + rg * (anh[rr] + bnh));
        float hnew = (1.f - zg) * ng + zg * h1f[row][c];
        h1f[row][c] = hnew;
        unsigned short hb = f2bf(hnew);
        A0[row][32 + c] = hb;   // next step's layer-0 A
        A1[row][c]      = hb;   // this step's layer-1 A (x-part)
      }
    }
    __syncthreads();  // s3: h1_new fully written

    // ---- layer 1 ----
    frag_ab a1[KT1];
    #pragma unroll
    for (int kt = 0; kt < KT1; ++kt)
      a1[kt] = *(const frag_ab*)&A1[c16][kt * 32 + q * 8];
    __syncthreads();  // s4: all A1 reads done before h2 stores

    #pragma unroll
    for (int jj = 0; jj < 2; ++jj) {
      const int j = j0 + jj;
      const char* pr = wb + ((size_t)(L0_FRAGS + (j     ) * KT1) << 10) + (size_t)(lane << 4);
      const char* pz = wb + ((size_t)(L0_FRAGS + (16 + j) * KT1) << 10) + (size_t)(lane << 4);
      const char* pn = wb + ((size_t)(L0_FRAGS + (32 + j) * KT1) << 10) + (size_t)(lane << 4);
      f32x4 ar = {0,0,0,0}, az = {0,0,0,0}, anx = {0,0,0,0}, anh = {0,0,0,0};
      #pragma unroll
      for (int kt = 0; kt < KT1; ++kt) {
        frag_ab br = *(const frag_ab*)(pr + kt * 1024);
        frag_ab bz = *(const frag_ab*)(pz + kt * 1024);
        frag_ab bn = *(const frag_ab*)(pn + kt * 1024);
        ar = mfma16(a1[kt], br, ar);
        az = mfma16(a1[kt], bz, az);
        if (kt < 8) anx = mfma16(a1[kt], bn, anx);   // W_ih1 @ h1_new
        else        anh = mfma16(a1[kt], bn, anh);   // W_hh1 @ h2
      }
      const int c   = j * 16 + c16;
      const float bri = sb[2*G3 + c],           brh = sb[3*G3 + c];
      const float bzi = sb[2*G3 + HID + c],     bzh = sb[3*G3 + HID + c];
      const float bni = sb[2*G3 + 2*HID + c],   bnh = sb[3*G3 + 2*HID + c];
      #pragma unroll
      for (int rr = 0; rr < 4; ++rr) {
        int row = q * 4 + rr;
        float rg = sigmoidf_(ar[rr] + bri + brh);
        float zg = sigmoidf_(az[rr] + bzi + bzh);
        float ng = tanhf_(anx[rr] + bni + rg * (anh[rr] + bnh));
        float hnew = (1.f - zg) * ng + zg * h2f[row][c];
        h2f[row][c] = hnew;
        A1[row][HID + c] = f2bf(hnew);  // next step's layer-1 h2 A-part
      }
    }
    // no barrier needed here: next-iter s1 orders h2 stores vs. a1 loads
  }

  __syncthreads();
  // ---- FC head: logits = h2 @ fc_w^T + fc_b; out = sigmoid*2-1 ----
  if (tid < ROWS * 4) {
    int row = tid >> 2, o = tid & 3;
    const float* wrow = &sb[4*G3 + o * HID];
    float acc = sb[4*G3 + 4*HID + o];
    #pragma unroll 8
    for (int k = 0; k < HID; ++k) acc += h2f[row][k] * wrow[k];
    float sg = 1.f / (1.f + __expf(-acc));
    out[(size_t)(brow0 + row) * 4 + o] = sg * 2.f - 1.f;
  }
}

extern "C" void kernel_launch(void* const* d_in, const int* in_sizes, int n_in,
                              void* d_out, int out_size, void* d_ws, size_t ws_size,
                              hipStream_t stream) {
  const float* x    = (const float*)d_in[0];
  const float* Wih0 = (const float*)d_in[1];
  const float* Whh0 = (const float*)d_in[2];
  const float* bih0 = (const float*)d_in[3];
  const float* bhh0 = (const float*)d_in[4];
  const float* Wih1 = (const float*)d_in[5];
  const float* Whh1 = (const float*)d_in[6];
  const float* bih1 = (const float*)d_in[7];
  const float* bhh1 = (const float*)d_in[8];
  const float* fcw  = (const float*)d_in[9];
  const float* fcb  = (const float*)d_in[10];
  unsigned short* wq = (unsigned short*)d_ws;  // 1.2 MB fragment buffer

  repack_w<<<(TOT_FRAGS * 64 + 255) / 256, 256, 0, stream>>>(Wih0, Whh0, Wih1, Whh1, wq);
  gru_fused<<<NBLK, TPB, 0, stream>>>(x, bih0, bhh0, bih1, bhh1, fcw, fcb, wq,
                                      (float*)d_out);
}

// Round 2
// 3519.973 us; speedup vs baseline: 1.3182x; 1.3182x over previous
//
#include <hip/hip_runtime.h>
#include <hip/hip_bf16.h>
#include <stdint.h>

// Problem constants
#define T_STEPS 128
#define BATCH   2048
#define IN_DIM  18
#define HID     256
#define G3      768   // 3*HID

// Tiling
#define NT   48              // 768 / 16 n-tiles
#define KT0  9               // layer0 k-tiles: 1 (x padded to 32) + 8 (h1, K=256)
#define KT1  16              // layer1 k-tiles: 8 (W_ih1) + 8 (W_hh1)
#define L0_FRAGS (NT * KT0)  // 432
#define L1_FRAGS (NT * KT1)  // 768
#define TOT_FRAGS (L0_FRAGS + L1_FRAGS)  // 1200 fragments x 1KB in d_ws

#define NBLK 128
#define TPB  1024            // 16 waves; wave j owns gate-triple j (cols 16j..16j+15)
#define ROWS 16              // batch rows per block
#define PITCH0 288           // bf16 pitch (576 B = 36*16, keeps b128 alignment)
#define PITCH1 544           // 1088 B = 68*16
#define HP     260           // fp32 h-state pitch

using frag_ab = __attribute__((ext_vector_type(8))) short;  // 8 x bf16 (4 VGPRs)
using f32x4   = __attribute__((ext_vector_type(4))) float;

__device__ __forceinline__ unsigned short f2bf(float f) {
  unsigned int u = __float_as_uint(f);
  u = (u + 0x7fffu + ((u >> 16) & 1u)) >> 16;  // RNE
  return (unsigned short)u;
}
__device__ __forceinline__ float sigmoidf_(float v) {
  return 1.f / (1.f + __expf(-v));
}
__device__ __forceinline__ float tanhf_(float v) {
  float a = fabsf(v);
  float e = __expf(-2.f * a);
  float r = (1.f - e) / (1.f + e);
  return v < 0.f ? -r : r;
}
__device__ __forceinline__ f32x4 mfma16(frag_ab a, frag_ab b, f32x4 c) {
  return __builtin_amdgcn_mfma_f32_16x16x32_bf16(a, b, c, 0, 0, 0);
}

// ---------------------------------------------------------------------------
// Prologue: fp32 weights -> bf16, permuted into exact MFMA B-fragment order.
// Fragment f (1KB): lane L, elems j hold B[k=kt*32+(L>>4)*8+j][n=ntile*16+(L&15)]
// where B[k][n] = W[n][k].
// ---------------------------------------------------------------------------
__global__ __launch_bounds__(256) void repack_w(
    const float* __restrict__ Wih0, const float* __restrict__ Whh0,
    const float* __restrict__ Wih1, const float* __restrict__ Whh1,
    unsigned short* __restrict__ wq)
{
  int g = blockIdx.x * 256 + threadIdx.x;
  if (g >= TOT_FRAGS * 64) return;
  int f = g >> 6;
  int L = g & 63;
  int q = L >> 4, c16 = L & 15;
  unsigned short v[8];
  if (f < L0_FRAGS) {
    int n = f / KT0, kt = f - n * KT0;
    int col = n * 16 + c16;
    if (kt == 0) {
      #pragma unroll
      for (int j = 0; j < 8; ++j) {
        int k = q * 8 + j;
        v[j] = (k < IN_DIM) ? f2bf(Wih0[col * IN_DIM + k]) : (unsigned short)0;
      }
    } else {
      int kb = (kt - 1) * 32 + q * 8;
      #pragma unroll
      for (int j = 0; j < 8; ++j) v[j] = f2bf(Whh0[col * HID + kb + j]);
    }
  } else {
    int f1 = f - L0_FRAGS;
    int n = f1 / KT1, kt = f1 - n * KT1;
    int col = n * 16 + c16;
    const float* __restrict__ W = (kt < 8) ? Wih1 : Whh1;
    int kb = (kt & 7) * 32 + q * 8;
    #pragma unroll
    for (int j = 0; j < 8; ++j) v[j] = f2bf(W[col * HID + kb + j]);
  }
  frag_ab pv;
  #pragma unroll
  for (int j = 0; j < 8; ++j) pv[j] = (short)v[j];
  *(frag_ab*)((char*)wq + ((size_t)f << 10) + (size_t)(L << 4)) = pv;
}

// ---------------------------------------------------------------------------
// Persistent fused 2-layer GRU + FC head. 16 waves; wave j owns h-cols
// [16j,16j+16) for both layers. Double-buffered LDS A-operands (parity t&1)
// -> exactly ONE __syncthreads per timestep. fp32 master h in LDS.
// ---------------------------------------------------------------------------
__global__ __launch_bounds__(TPB, 4) void gru_fused(
    const float* __restrict__ x,
    const float* __restrict__ bih0, const float* __restrict__ bhh0,
    const float* __restrict__ bih1, const float* __restrict__ bhh1,
    const float* __restrict__ fcw,  const float* __restrict__ fcb,
    const unsigned short* __restrict__ wq,
    float* __restrict__ out)
{
  __shared__ __align__(16) unsigned short A0[2][ROWS][PITCH0]; // [x pad32 | h1]
  __shared__ __align__(16) unsigned short A1[2][ROWS][PITCH1]; // [h1_new | h2 | pad]
  __shared__ float h1f[ROWS][HP];
  __shared__ float h2f[ROWS][HP];
  __shared__ float sb[4 * G3 + 4 * HID + 4];

  const int tid  = threadIdx.x;
  const int wave = tid >> 6;          // 0..15 = col-group
  const int lane = tid & 63;
  const int q    = lane >> 4;
  const int c16  = lane & 15;
  const int brow0 = blockIdx.x * ROWS;

  for (int i = tid; i < 2 * ROWS * PITCH0; i += TPB) (&A0[0][0][0])[i] = 0;
  for (int i = tid; i < 2 * ROWS * PITCH1; i += TPB) (&A1[0][0][0])[i] = 0;
  for (int i = tid; i < ROWS * HP; i += TPB) { (&h1f[0][0])[i] = 0.f; (&h2f[0][0])[i] = 0.f; }
  for (int i = tid; i < G3; i += TPB) {
    sb[i]          = bih0[i];
    sb[G3 + i]     = bhh0[i];
    sb[2*G3 + i]   = bih1[i];
    sb[3*G3 + i]   = bhh1[i];
  }
  for (int i = tid; i < 4 * HID; i += TPB) sb[4*G3 + i] = fcw[i];
  if (tid < 4) sb[4*G3 + 4*HID + tid] = fcb[tid];
  // stage x_0 into A0[0]
  if (tid < ROWS * IN_DIM) {
    int r = tid / IN_DIM, cc = tid - r * IN_DIM;
    A0[0][r][cc] = f2bf(x[(size_t)brow0 * IN_DIM + tid]);
  }
  __syncthreads();

  const char* wqc = (const char*)wq;
  const int vo = lane << 4;
  // uniform byte offsets of this wave's fragment streams
  const int b0r = ( wave        * KT0) << 10;
  const int b0z = ((16 + wave)  * KT0) << 10;
  const int b0n = ((32 + wave)  * KT0) << 10;
  const int b1r = ((L0_FRAGS +  wave        * KT1) ) << 10;
  const int b1z = ((L0_FRAGS + (16 + wave) * KT1) ) << 10;
  const int b1n = ((L0_FRAGS + (32 + wave) * KT1) ) << 10;

  const int c = wave * 16 + c16;   // this lane's h-column
  const float l0_bri = sb[c],           l0_brh = sb[G3 + c];
  const float l0_bzi = sb[HID + c],     l0_bzh = sb[G3 + HID + c];
  const float l0_bni = sb[2*HID + c],   l0_bnh = sb[G3 + 2*HID + c];
  const float l1_bri = sb[2*G3 + c],         l1_brh = sb[3*G3 + c];
  const float l1_bzi = sb[2*G3 + HID + c],   l1_bzh = sb[3*G3 + HID + c];
  const float l1_bni = sb[2*G3 + 2*HID + c], l1_bnh = sb[3*G3 + 2*HID + c];

  #define LDW(base, kt) (*(const frag_ab*)(wqc + (base) + ((kt) << 10) + vo))

  for (int t = 0; t < T_STEPS; ++t) {
    const int p = t & 1, np = p ^ 1;

    // ---- x_{t+1} prefetch (global -> reg), written to A0[np] before barrier
    float xv = 0.f;
    const bool hasx = (t + 1 < T_STEPS) && (tid < ROWS * IN_DIM);
    if (hasx) xv = x[(size_t)((t + 1) * BATCH + brow0) * IN_DIM + tid];

    // ================= Layer 0 =================
    {
      f32x4 ar = {0,0,0,0}, az = {0,0,0,0}, anx = {0,0,0,0}, anh = {0,0,0,0};
      frag_ab br[3], bz[3], bn[3], af[2];
      br[0] = LDW(b0r, 0); bz[0] = LDW(b0z, 0); bn[0] = LDW(b0n, 0);
      br[1] = LDW(b0r, 1); bz[1] = LDW(b0z, 1); bn[1] = LDW(b0n, 1);
      af[0] = *(const frag_ab*)&A0[p][c16][q * 8];
      #pragma unroll
      for (int kt = 0; kt < KT0; ++kt) {
        const int cur = kt % 3, nx2 = (kt + 2) % 3;
        if (kt + 2 < KT0) {
          br[nx2] = LDW(b0r, kt + 2);
          bz[nx2] = LDW(b0z, kt + 2);
          bn[nx2] = LDW(b0n, kt + 2);
        }
        if (kt + 1 < KT0)
          af[(kt + 1) & 1] = *(const frag_ab*)&A0[p][c16][(kt + 1) * 32 + q * 8];
        const frag_ab a = af[kt & 1];
        ar = mfma16(a, br[cur], ar);
        az = mfma16(a, bz[cur], az);
        if (kt == 0) anx = mfma16(a, bn[cur], anx);
        else         anh = mfma16(a, bn[cur], anh);
      }
      // park x_{t+1} into next buffer (cols < 18; pad cols stay 0 from init)
      if (hasx) {
        int r = tid / IN_DIM, cc = tid - r * IN_DIM;
        A0[np][r][cc] = f2bf(xv);
      }
      #pragma unroll
      for (int rr = 0; rr < 4; ++rr) {
        const int row = q * 4 + rr;   // C/D: row=(lane>>4)*4+reg, col=lane&15
        float rg = sigmoidf_(ar[rr] + l0_bri + l0_brh);
        float zg = sigmoidf_(az[rr] + l0_bzi + l0_bzh);
        float ng = tanhf_(anx[rr] + l0_bni + rg * (anh[rr] + l0_bnh));
        float hnew = (1.f - zg) * ng + zg * h1f[row][c];
        h1f[row][c] = hnew;
        unsigned short hb = f2bf(hnew);
        A0[np][row][32 + c] = hb;   // next step's layer-0 A
        A1[p][row][c]       = hb;   // this step's layer-1 A (x-part)
      }
    }
    __syncthreads();   // the ONE barrier: h1_new visible; also fences x/h writes

    // ================= Layer 1 =================
    {
      f32x4 ar = {0,0,0,0}, az = {0,0,0,0}, anx = {0,0,0,0}, anh = {0,0,0,0};
      frag_ab br[3], bz[3], bn[3], af[2];
      br[0] = LDW(b1r, 0); bz[0] = LDW(b1z, 0); bn[0] = LDW(b1n, 0);
      br[1] = LDW(b1r, 1); bz[1] = LDW(b1z, 1); bn[1] = LDW(b1n, 1);
      af[0] = *(const frag_ab*)&A1[p][c16][q * 8];
      #pragma unroll
      for (int kt = 0; kt < KT1; ++kt) {
        const int cur = kt % 3, nx2 = (kt + 2) % 3;
        if (kt + 2 < KT1) {
          br[nx2] = LDW(b1r, kt + 2);
          bz[nx2] = LDW(b1z, kt + 2);
          bn[nx2] = LDW(b1n, kt + 2);
        }
        if (kt + 1 < KT1)
          af[(kt + 1) & 1] = *(const frag_ab*)&A1[p][c16][(kt + 1) * 32 + q * 8];
        const frag_ab a = af[kt & 1];
        ar = mfma16(a, br[cur], ar);
        az = mfma16(a, bz[cur], az);
        if (kt < 8) anx = mfma16(a, bn[cur], anx);   // W_ih1 @ h1_new
        else        anh = mfma16(a, bn[cur], anh);   // W_hh1 @ h2
      }
      #pragma unroll
      for (int rr = 0; rr < 4; ++rr) {
        const int row = q * 4 + rr;
        float rg = sigmoidf_(ar[rr] + l1_bri + l1_brh);
        float zg = sigmoidf_(az[rr] + l1_bzi + l1_bzh);
        float ng = tanhf_(anx[rr] + l1_bni + rg * (anh[rr] + l1_bnh));
        float hnew = (1.f - zg) * ng + zg * h2f[row][c];
        h2f[row][c] = hnew;
        A1[np][row][HID + c] = f2bf(hnew);  // next step's layer-1 h2 A-part
      }
    }
    // no end-of-step barrier: next step's reads are fenced by its mid-step
    // barrier (all cross-wave consumers sit behind the next __syncthreads)
  }

  __syncthreads();
  // ---- FC head ----
  if (tid < ROWS * 4) {
    int row = tid >> 2, o = tid & 3;
    const float* wrow = &sb[4*G3 + o * HID];
    float acc = sb[4*G3 + 4*HID + o];
    #pragma unroll 8
    for (int k = 0; k < HID; ++k) acc += h2f[row][k] * wrow[k];
    float sg = 1.f / (1.f + __expf(-acc));
    out[(size_t)(brow0 + row) * 4 + o] = sg * 2.f - 1.f;
  }
  #undef LDW
}

extern "C" void kernel_launch(void* const* d_in, const int* in_sizes, int n_in,
                              void* d_out, int out_size, void* d_ws, size_t ws_size,
                              hipStream_t stream) {
  const float* x    = (const float*)d_in[0];
  const float* Wih0 = (const float*)d_in[1];
  const float* Whh0 = (const float*)d_in[2];
  const float* bih0 = (const float*)d_in[3];
  const float* bhh0 = (const float*)d_in[4];
  const float* Wih1 = (const float*)d_in[5];
  const float* Whh1 = (const float*)d_in[6];
  const float* bih1 = (const float*)d_in[7];
  const float* bhh1 = (const float*)d_in[8];
  const float* fcw  = (const float*)d_in[9];
  const float* fcb  = (const float*)d_in[10];
  unsigned short* wq = (unsigned short*)d_ws;

  repack_w<<<(TOT_FRAGS * 64 + 255) / 256, 256, 0, stream>>>(Wih0, Whh0, Wih1, Whh1, wq);
  gru_fused<<<NBLK, TPB, 0, stream>>>(x, bih0, bhh0, bih1, bhh1, fcw, fcb, wq,
                                      (float*)d_out);
}

// Round 3
// 2120.107 us; speedup vs baseline: 2.1886x; 1.6603x over previous
//
#include <hip/hip_runtime.h>
#include <hip/hip_bf16.h>
#include <stdint.h>

// Problem constants
#define T_STEPS 128
#define BATCH   2048
#define IN_DIM  18
#define HID     256
#define G3      768   // 3*HID

// Tiling
#define NT   48              // 768 / 16 n-tiles
#define KT0  9               // layer0 k-tiles: 1 (x padded to 32) + 8 (h1, K=256)
#define KT1  16              // layer1 k-tiles: 8 (W_ih1) + 8 (W_hh1)
#define L0_FRAGS (NT * KT0)  // 432
#define L1_FRAGS (NT * KT1)  // 768
#define TOT_FRAGS (L0_FRAGS + L1_FRAGS)  // 1200 fragments x 1KB in d_ws

#define NBLK 128
#define TPB  1024            // 16 waves; wave j owns gate-triple j (cols 16j..16j+15)
#define ROWS 16
#define PITCH0 288           // bf16; 576 B row stride (16B-aligned)
#define PITCH1 544           // 1088 B row stride

using frag_ab = __attribute__((ext_vector_type(8))) short;  // 8 x bf16 (4 VGPRs)
using f32x4   = __attribute__((ext_vector_type(4))) float;

__device__ __forceinline__ unsigned short f2bf(float f) {
  unsigned int u = __float_as_uint(f);
  u = (u + 0x7fffu + ((u >> 16) & 1u)) >> 16;  // RNE
  return (unsigned short)u;
}
__device__ __forceinline__ float sigmoidf_(float v) {
  return 1.f / (1.f + __expf(-v));
}
__device__ __forceinline__ float tanhf_(float v) {
  float a = fabsf(v);
  float e = __expf(-2.f * a);
  float r = (1.f - e) / (1.f + e);
  return v < 0.f ? -r : r;
}
__device__ __forceinline__ f32x4 mfma16(frag_ab a, frag_ab b, f32x4 c) {
  return __builtin_amdgcn_mfma_f32_16x16x32_bf16(a, b, c, 0, 0, 0);
}

// ---------------------------------------------------------------------------
// Prologue: fp32 weights -> bf16, permuted into exact MFMA B-fragment order.
// Fragment f (1KB): lane L, elems j hold B[k=kt*32+(L>>4)*8+j][n=ntile*16+(L&15)]
// where B[k][n] = W[n][k].
// ---------------------------------------------------------------------------
__global__ __launch_bounds__(256) void repack_w(
    const float* __restrict__ Wih0, const float* __restrict__ Whh0,
    const float* __restrict__ Wih1, const float* __restrict__ Whh1,
    unsigned short* __restrict__ wq)
{
  int g = blockIdx.x * 256 + threadIdx.x;
  if (g >= TOT_FRAGS * 64) return;
  int f = g >> 6;
  int L = g & 63;
  int q = L >> 4, c16 = L & 15;
  unsigned short v[8];
  if (f < L0_FRAGS) {
    int n = f / KT0, kt = f - n * KT0;
    int col = n * 16 + c16;
    if (kt == 0) {
      #pragma unroll
      for (int j = 0; j < 8; ++j) {
        int k = q * 8 + j;
        v[j] = (k < IN_DIM) ? f2bf(Wih0[col * IN_DIM + k]) : (unsigned short)0;
      }
    } else {
      int kb = (kt - 1) * 32 + q * 8;
      #pragma unroll
      for (int j = 0; j < 8; ++j) v[j] = f2bf(Whh0[col * HID + kb + j]);
    }
  } else {
    int f1 = f - L0_FRAGS;
    int n = f1 / KT1, kt = f1 - n * KT1;
    int col = n * 16 + c16;
    const float* __restrict__ W = (kt < 8) ? Wih1 : Whh1;
    int kb = (kt & 7) * 32 + q * 8;
    #pragma unroll
    for (int j = 0; j < 8; ++j) v[j] = f2bf(W[col * HID + kb + j]);
  }
  frag_ab pv;
  #pragma unroll
  for (int j = 0; j < 8; ++j) pv[j] = (short)v[j];
  *(frag_ab*)((char*)wq + ((size_t)f << 10) + (size_t)(L << 4)) = pv;
}

// ---------------------------------------------------------------------------
// Persistent fused 2-layer GRU + FC head, hand-pipelined weight stream:
// depth-5 register ring of B-frag triples via asm global_load_dwordx4,
// explicit s_waitcnt vmcnt(N), raw s_barrier (no vm drain) -> the vm queue
// stays >= 4 triples deep across all 128 steps, including across barriers.
// ---------------------------------------------------------------------------
__global__ __launch_bounds__(TPB, 4) void gru_fused(
    const float* __restrict__ x,
    const float* __restrict__ bih0, const float* __restrict__ bhh0,
    const float* __restrict__ bih1, const float* __restrict__ bhh1,
    const float* __restrict__ fcw,  const float* __restrict__ fcb,
    const unsigned short* __restrict__ wq,
    float* __restrict__ out)
{
  __shared__ __align__(16) unsigned short A0[2][ROWS][PITCH0]; // [x pad32 | h1]
  __shared__ __align__(16) unsigned short A1[2][ROWS][PITCH1]; // [h1_new | h2 | pad]
  __shared__ float h2fc[ROWS][257];                            // final h2 fp32 for FC

  const int tid  = threadIdx.x;
  const int wave = tid >> 6;          // 0..15 = col-group = batch row for x-stage
  const int lane = tid & 63;
  const int q    = lane >> 4;
  const int c16  = lane & 15;
  const int brow0 = blockIdx.x * ROWS;
  const uint32_t lane16 = (uint32_t)(lane << 4);

  for (int i = tid; i < 2 * ROWS * PITCH0; i += TPB) (&A0[0][0][0])[i] = 0;
  for (int i = tid; i < 2 * ROWS * PITCH1; i += TPB) (&A1[0][0][0])[i] = 0;

  const int c = wave * 16 + c16;      // this lane's h-column (0..255)
  // combined biases, registers only
  const float l0_brc = bih0[c]           + bhh0[c];
  const float l0_bzc = bih0[HID + c]     + bhh0[HID + c];
  const float l0_bni = bih0[2*HID + c];
  const float l0_bnh = bhh0[2*HID + c];
  const float l1_brc = bih1[c]           + bhh1[c];
  const float l1_bzc = bih1[HID + c]     + bhh1[HID + c];
  const float l1_bni = bih1[2*HID + c];
  const float l1_bnh = bhh1[2*HID + c];

  // stage x_0 into A0[0]: wave w = row w, lanes 0..17 = cols
  if (lane < IN_DIM)
    A0[0][wave][lane] = f2bf(x[(size_t)(brow0 + wave) * IN_DIM + lane]);
  __syncthreads();   // init barrier (drains everything; pipeline starts clean)

  // per-wave fragment-stream byte bases in wq
  const uint32_t b0r = (uint32_t)(( wave       * KT0) << 10);
  const uint32_t b0z = (uint32_t)(((16 + wave) * KT0) << 10);
  const uint32_t b0n = (uint32_t)(((32 + wave) * KT0) << 10);
  const uint32_t b1r = (uint32_t)((L0_FRAGS +  wave       * KT1) << 10);
  const uint32_t b1z = (uint32_t)((L0_FRAGS + (16 + wave) * KT1) << 10);
  const uint32_t b1n = (uint32_t)((L0_FRAGS + (32 + wave) * KT1) << 10);

  frag_ab rr_[5], rz_[5], rn_[5];     // depth-5 register ring (60 VGPRs, pinned)
  float h1m[4] = {0.f, 0.f, 0.f, 0.f};
  float h2m[4] = {0.f, 0.f, 0.f, 0.f};
  uint32_t xvu = 0;

#define ISSUE3(sl, oR, oZ, oN)                                              \
  asm volatile("global_load_dwordx4 %0, %3, %6\n\t"                         \
               "global_load_dwordx4 %1, %4, %6\n\t"                         \
               "global_load_dwordx4 %2, %5, %6"                             \
               : "=&v"(rr_[sl]), "=&v"(rz_[sl]), "=&v"(rn_[sl])             \
               : "v"((uint32_t)(oR)), "v"((uint32_t)(oZ)),                  \
                 "v"((uint32_t)(oN)), "s"(wq)                               \
               : "memory")
#define WAIT3(sl, NSTR)                                                     \
  asm volatile("s_waitcnt vmcnt(" NSTR ")"                                  \
               : "+v"(rr_[sl]), "+v"(rz_[sl]), "+v"(rn_[sl]) :: "memory")
#define BARRIER() asm volatile("s_waitcnt lgkmcnt(0)\n\ts_barrier" ::: "memory")

  // prologue: fill the ring with L0 triples T0..T4
  #pragma unroll
  for (int i = 0; i < 5; ++i)
    ISSUE3(i, b0r + i * 1024 + lane16, b0z + i * 1024 + lane16,
              b0n + i * 1024 + lane16);

  for (int t = 0; t < T_STEPS; ++t) {
    const int p = t & 1, np = p ^ 1;

    // ================= Layer 0 (9 triples, local 0..8) =================
    f32x4 ar = {0,0,0,0}, az = {0,0,0,0}, anx = {0,0,0,0}, anh = {0,0,0,0};
    #pragma unroll
    for (int kt = 0; kt < KT0; ++kt) {
      const int sl = kt % 5;
      // in-order vmcnt: see schedule derivation (x sits between T5 and T6)
      if (kt == 0)      { WAIT3(sl, "12"); }
      else if (kt <= 5) { WAIT3(sl, "13"); }
      else              { WAIT3(sl, "12"); }
      const frag_ab a = *(const frag_ab*)&A0[p][c16][kt * 32 + q * 8];
      ar = mfma16(a, rr_[sl], ar);
      az = mfma16(a, rz_[sl], az);
      if (kt == 0) anx = mfma16(a, rn_[sl], anx);
      else         anh = mfma16(a, rn_[sl], anh);
      if (kt + 5 < KT0) {            // kt=0..3 -> issue L0 T5..T8
        const uint32_t o = (uint32_t)(kt + 5) * 1024 + lane16;
        ISSUE3(sl, b0r + o, b0z + o, b0n + o);
      } else {                        // kt=4..8 -> issue L1 triples 0..4
        const uint32_t o = (uint32_t)(kt - 4) * 1024 + lane16;
        ISSUE3(sl, b1r + o, b1z + o, b1n + o);
      }
      if (kt == 0) {                  // x_{t+1} prefetch (1 vm op, all waves)
        const int t1 = (t < T_STEPS - 1) ? t + 1 : t;
        const uint32_t xoff =
            (uint32_t)(((t1 * BATCH + brow0) * IN_DIM
                        + wave * IN_DIM + (lane < IN_DIM ? lane : IN_DIM - 1))
                       * 4);
        asm volatile("global_load_dword %0, %1, %2"
                     : "=&v"(xvu) : "v"(xoff), "s"(x) : "memory");
      }
    }
    // ---- L0 epilogue ----
    asm volatile("s_waitcnt vmcnt(24)" : "+v"(xvu) :: "memory"); // x done (free)
    if (lane < IN_DIM)
      A0[np][wave][lane] = f2bf(__uint_as_float(xvu));
    #pragma unroll
    for (int rrI = 0; rrI < 4; ++rrI) {
      const int row = q * 4 + rrI;   // C/D: row=(lane>>4)*4+reg, col=lane&15
      float rg = sigmoidf_(ar[rrI] + l0_brc);
      float zg = sigmoidf_(az[rrI] + l0_bzc);
      float ng = tanhf_(anx[rrI] + l0_bni + rg * (anh[rrI] + l0_bnh));
      float hnew = (1.f - zg) * ng + zg * h1m[rrI];
      h1m[rrI] = hnew;
      unsigned short hb = f2bf(hnew);
      A0[np][row][32 + c] = hb;   // next step's layer-0 A
      A1[p][row][c]       = hb;   // this step's layer-1 A (x-part)
    }
    BARRIER();   // the ONE barrier per step; vm queue stays loaded across it

    // ================= Layer 1 (16 triples, local 9..24) =================
    ar = (f32x4){0,0,0,0}; az = (f32x4){0,0,0,0};
    anx = (f32x4){0,0,0,0}; anh = (f32x4){0,0,0,0};
    #pragma unroll
    for (int kt = 0; kt < KT1; ++kt) {
      const int sl = (9 + kt) % 5;
      WAIT3(sl, "12");
      const frag_ab a = *(const frag_ab*)&A1[p][c16][kt * 32 + q * 8];
      ar = mfma16(a, rr_[sl], ar);
      az = mfma16(a, rz_[sl], az);
      if (kt < 8) anx = mfma16(a, rn_[sl], anx);   // W_ih1 @ h1_new
      else        anh = mfma16(a, rn_[sl], anh);   // W_hh1 @ h2
      if (kt < 11) {                  // issue L1 triples kt+5
        const uint32_t o = (uint32_t)(kt + 5) * 1024 + lane16;
        ISSUE3(sl, b1r + o, b1z + o, b1n + o);
      } else {                        // kt=11..15 -> next step's L0 T0..T4
        const uint32_t o = (uint32_t)(kt - 11) * 1024 + lane16;
        ISSUE3(sl, b0r + o, b0z + o, b0n + o);
      }
    }
    // ---- L1 epilogue ----
    #pragma unroll
    for (int rrI = 0; rrI < 4; ++rrI) {
      const int row = q * 4 + rrI;
      float rg = sigmoidf_(ar[rrI] + l1_brc);
      float zg = sigmoidf_(az[rrI] + l1_bzc);
      float ng = tanhf_(anx[rrI] + l1_bni + rg * (anh[rrI] + l1_bnh));
      float hnew = (1.f - zg) * ng + zg * h2m[rrI];
      h2m[rrI] = hnew;
      A1[np][row][HID + c] = f2bf(hnew);  // next step's layer-1 h2 A-part
      if (t == T_STEPS - 1) h2fc[row][c] = hnew;
    }
    // no end-of-step barrier (mid-step barrier of step t+1 orders everything)
  }

  asm volatile("s_waitcnt vmcnt(0)" ::: "memory");  // drain tail prefetches
  __syncthreads();

  // ---- FC head: logits = h2 @ fc_w^T + fc_b; out = sigmoid*2-1 ----
  if (tid < ROWS * 4) {
    int row = tid >> 2, o = tid & 3;
    const float* wrow = &fcw[o * HID];
    float acc = fcb[o];
    #pragma unroll 8
    for (int k = 0; k < HID; ++k) acc += h2fc[row][k] * wrow[k];
    float sg = 1.f / (1.f + __expf(-acc));
    out[(size_t)(brow0 + row) * 4 + o] = sg * 2.f - 1.f;
  }
#undef ISSUE3
#undef WAIT3
#undef BARRIER
}

extern "C" void kernel_launch(void* const* d_in, const int* in_sizes, int n_in,
                              void* d_out, int out_size, void* d_ws, size_t ws_size,
                              hipStream_t stream) {
  const float* x    = (const float*)d_in[0];
  const float* Wih0 = (const float*)d_in[1];
  const float* Whh0 = (const float*)d_in[2];
  const float* bih0 = (const float*)d_in[3];
  const float* bhh0 = (const float*)d_in[4];
  const float* Wih1 = (const float*)d_in[5];
  const float* Whh1 = (const float*)d_in[6];
  const float* bih1 = (const float*)d_in[7];
  const float* bhh1 = (const float*)d_in[8];
  const float* fcw  = (const float*)d_in[9];
  const float* fcb  = (const float*)d_in[10];
  unsigned short* wq = (unsigned short*)d_ws;

  repack_w<<<(TOT_FRAGS * 64 + 255) / 256, 256, 0, stream>>>(Wih0, Whh0, Wih1, Whh1, wq);
  gru_fused<<<NBLK, TPB, 0, stream>>>(x, bih0, bhh0, bih1, bhh1, fcw, fcb, wq,
                                      (float*)d_out);
}